// Round 1
// baseline (636.773 us; speedup 1.0000x reference)
//
#include <hip/hip_runtime.h>
#include <math.h>

#define BB 4
#define TT 200
#define UU 101
#define VV 1024
#define NCELL (BB*TT*UU)   // 80800

__device__ __forceinline__ float f4max(const float4& v) {
    return fmaxf(fmaxf(v.x, v.y), fmaxf(v.z, v.w));
}
__device__ __forceinline__ float f4comp(const float4& v, int c) {
    switch (c & 3) { case 0: return v.x; case 1: return v.y; case 2: return v.z; default: return v.w; }
}

// Kernel 1: one 64-lane wave per (b,t,u) cell. Computes logsumexp over V=1024,
// writes blank_lp[b,t,u] and label_lp[b,t,u] (for u < lab).
// Data-dependent skip: cells with u > lab_lens[b] never reach the loss
// (alpha is only read at (tmax, lab)), so skip their 4 KB logits read entirely.
__global__ __launch_bounds__(256) void lse_kernel(
        const float* __restrict__ logits,
        const int*   __restrict__ labels,     // [B, U-1]
        const int*   __restrict__ lab_lens,   // [B]
        float* __restrict__ blank_lp,         // [B, T, U]
        float* __restrict__ label_lp) {       // [B, T, U-1]
    const int wave = threadIdx.x >> 6;
    const int lane = threadIdx.x & 63;
    const int cell = blockIdx.x * 4 + wave;
    if (cell >= NCELL) return;
    const int b   = cell / (TT * UU);
    const int rem = cell % (TT * UU);
    const int t   = rem / UU;
    const int u   = rem % UU;

    int lab = lab_lens[b];
    lab = min(max(lab, 0), UU - 1);
    if (u > lab) return;                      // dead cell: skip the read

    const float4* src = (const float4*)(logits + (size_t)cell * VV);
    float4 x0 = src[lane];
    float4 x1 = src[lane + 64];
    float4 x2 = src[lane + 128];
    float4 x3 = src[lane + 192];

    float m = fmaxf(fmaxf(f4max(x0), f4max(x1)), fmaxf(f4max(x2), f4max(x3)));
    #pragma unroll
    for (int off = 32; off; off >>= 1) m = fmaxf(m, __shfl_xor(m, off));

    float s = 0.f;
    s += __expf(x0.x - m) + __expf(x0.y - m) + __expf(x0.z - m) + __expf(x0.w - m);
    s += __expf(x1.x - m) + __expf(x1.y - m) + __expf(x1.z - m) + __expf(x1.w - m);
    s += __expf(x2.x - m) + __expf(x2.y - m) + __expf(x2.z - m) + __expf(x2.w - m);
    s += __expf(x3.x - m) + __expf(x3.y - m) + __expf(x3.z - m) + __expf(x3.w - m);
    #pragma unroll
    for (int off = 32; off; off >>= 1) s += __shfl_xor(s, off);

    const float lse = m + __logf(s);

    if (lane == 0) blank_lp[cell] = x0.x - lse;   // vocab index 0 lives in lane 0, x0.x

    if (u < lab) {                                // label_lp only consumed for u <= lab-1
        int l = labels[b * (UU - 1) + u];
        l = min(max(l, 0), VV - 1);
        const int lane_l = (l >> 2) & 63;
        if (lane == lane_l) {
            const int j = l >> 8;      // which float4 (0..3)
            const int c = l & 3;       // component
            float val = (j == 0) ? f4comp(x0, c) : (j == 1) ? f4comp(x1, c)
                      : (j == 2) ? f4comp(x2, c) : f4comp(x3, c);
            label_lp[(b * TT + t) * (UU - 1) + u] = val - lse;
        }
    }
}

// Kernel 2: wave-synchronous anti-diagonal alpha recursion + fused finalize.
// One 64-lane wave per batch (4 waves, 1 block). Lane l owns columns 2l, 2l+1.
// Cross-column dependency (alpha[t, u-1]) arrives via __shfl_up — no LDS, no
// __syncthreads in the 301-diagonal serial loop. Blank/label values register-
// prefetched 4 diagonals ahead to hide L2 latency.
__global__ __launch_bounds__(256) void alpha_kernel(
        const float* __restrict__ blank_lp,
        const float* __restrict__ label_lp,
        const int*   __restrict__ lab_lens,   // [B]
        const int*   __restrict__ attn,       // [B, T]
        float* __restrict__ out) {            // [1]
    const int b    = threadIdx.x >> 6;        // wave = batch
    const int lane = threadIdx.x & 63;

    // input length = clip(sum(attn[b,:]), 1, T), reduced within the wave
    int acc = 0;
    for (int i = lane; i < TT; i += 64) acc += attn[b * TT + i];
    #pragma unroll
    for (int off = 32; off; off >>= 1) acc += __shfl_xor(acc, off);
    int inlen = min(max(acc, 1), TT);
    const int tmax = inlen - 1;
    int lab = lab_lens[b];
    lab = min(max(lab, 0), UU - 1);
    const int ndiag = tmax + lab + 1;

    const float* bl = blank_lp + b * TT * UU;
    const float* lb = label_lp + b * TT * (UU - 1);

    const int u0 = lane * 2, u1 = u0 + 1;
    const int c0 = min(u0, UU - 1), c1 = min(u1, UU - 1);           // clamped blank col
    const int e0 = min(max(u0 - 1, 0), UU - 2), e1 = min(u1 - 1, UU - 2); // clamped label col

    auto fetch = [&](int d, float& fb0, float& fl0, float& fb1, float& fl1) {
        int t0 = min(max(d - u0, 0), TT - 1);
        int t1 = min(max(d - u1, 0), TT - 1);
        fb0 = bl[t0 * UU + c0];
        fl0 = lb[t0 * (UU - 1) + e0];
        fb1 = bl[t1 * UU + c1];
        fl1 = lb[t1 * (UU - 1) + e1];
    };

    float a0 = -INFINITY, a1 = -INFINITY;   // alpha at previous diagonal for my 2 cols

    float cb0[4], cl0[4], cb1[4], cl1[4];
    float nb0[4], nl0[4], nb1[4], nl1[4];
    #pragma unroll
    for (int k = 0; k < 4; ++k) fetch(k, cb0[k], cl0[k], cb1[k], cl1[k]);

    const int ng = (ndiag + 3) >> 2;
    for (int g = 0; g < ng; ++g) {
        const int dbase = g * 4;
        #pragma unroll
        for (int k = 0; k < 4; ++k) fetch(dbase + 4 + k, nb0[k], nl0[k], nb1[k], nl1[k]);
        #pragma unroll
        for (int k = 0; k < 4; ++k) {
            const int d = dbase + k;
            if (d < ndiag) {                      // wave-uniform branch
                const float left = __shfl_up(a1, 1);  // alpha[t0, u0-1] (prev diag of left col)
                const int t0 = d - u0;
                const int t1 = d - u1;
                float v0 = a0, v1 = a1;
                if (u0 <= lab && t0 >= 0 && t0 <= tmax) {
                    if (d == 0)        v0 = cb0[k];                 // alpha[0,0]
                    else if (u0 == 0)  v0 = a0 + cb0[k];            // blank-only column
                    else if (t0 == 0)  v0 = left + cl0[k];          // label-only row
                    else {
                        const float x = a0 + cb0[k], y = left + cl0[k];
                        const float mx = fmaxf(x, y), mn = fminf(x, y);
                        v0 = mx + __logf(1.f + __expf(mn - mx));
                    }
                }
                if (u1 <= lab && t1 >= 0 && t1 <= tmax) {           // u1 >= 1 always
                    if (t1 == 0)       v1 = a0 + cl1[k];            // label-only row
                    else {
                        const float x = a1 + cb1[k], y = a0 + cl1[k];
                        const float mx = fmaxf(x, y), mn = fminf(x, y);
                        v1 = mx + __logf(1.f + __expf(mn - mx));
                    }
                }
                a0 = v0; a1 = v1;                 // commit after both (v1 needs old a0)
            }
        }
        #pragma unroll
        for (int k = 0; k < 4; ++k) { cb0[k] = nb0[k]; cl0[k] = nl0[k];
                                      cb1[k] = nb1[k]; cl1[k] = nl1[k]; }
    }

    __shared__ float s_loss[BB];
    __shared__ int   s_valid[BB];
    if (u0 == lab) s_loss[b] = -a0;
    if (u1 == lab) s_loss[b] = -a1;
    if (lane == 0) s_valid[b] = (lab > 0) ? 1 : 0;
    __syncthreads();
    if (threadIdx.x == 0) {
        float s = 0.f; int nv = 0;
        for (int i = 0; i < BB; ++i) if (s_valid[i]) { s += s_loss[i]; ++nv; }
        out[0] = s / (float)max(nv, 1);
    }
}

extern "C" void kernel_launch(void* const* d_in, const int* in_sizes, int n_in,
                              void* d_out, int out_size, void* d_ws, size_t ws_size,
                              hipStream_t stream) {
    const float* logits   = (const float*)d_in[0];
    const int*   labels   = (const int*)d_in[1];
    const int*   lab_lens = (const int*)d_in[2];
    const int*   attn     = (const int*)d_in[3];

    float* ws    = (float*)d_ws;
    float* blank = ws;                           // B*T*U
    float* label = blank + BB * TT * UU;         // B*T*(U-1)

    lse_kernel<<<(NCELL + 3) / 4, 256, 0, stream>>>(logits, labels, lab_lens, blank, label);
    alpha_kernel<<<1, 256, 0, stream>>>(blank, label, lab_lens, attn, (float*)d_out);
}

// Round 2
// 473.667 us; speedup vs baseline: 1.3443x; 1.3443x over previous
//
#include <hip/hip_runtime.h>
#include <math.h>

#define BB 4
#define TT 200
#define UU 101
#define VV 1024
#define NCELL (BB*TT*UU)   // 80800
#define PAD 102            // LDS row pitch: lane stride 101 (odd) -> conflict-free

__device__ __forceinline__ float f4max(const float4& v) {
    return fmaxf(fmaxf(v.x, v.y), fmaxf(v.z, v.w));
}
__device__ __forceinline__ float f4comp(const float4& v, int c) {
    switch (c & 3) { case 0: return v.x; case 1: return v.y; case 2: return v.z; default: return v.w; }
}

// Kernel 1: one 64-lane wave per (b,t,u) cell. LSE over V=1024.
// Data-dependent skip: cells with u > lab never reach the loss.
__global__ __launch_bounds__(256) void lse_kernel(
        const float* __restrict__ logits,
        const int*   __restrict__ labels,     // [B, U-1]
        const int*   __restrict__ lab_lens,   // [B]
        float* __restrict__ blank_lp,         // [B, T, U]
        float* __restrict__ label_lp) {       // [B, T, U-1]
    const int wave = threadIdx.x >> 6;
    const int lane = threadIdx.x & 63;
    const int cell = blockIdx.x * 4 + wave;
    if (cell >= NCELL) return;
    const int b   = cell / (TT * UU);
    const int rem = cell % (TT * UU);
    const int t   = rem / UU;
    const int u   = rem % UU;

    int lab = lab_lens[b];
    lab = min(max(lab, 0), UU - 1);
    if (u > lab) return;                      // dead cell: skip the 4KB read

    const float4* src = (const float4*)(logits + (size_t)cell * VV);
    float4 x0 = src[lane];
    float4 x1 = src[lane + 64];
    float4 x2 = src[lane + 128];
    float4 x3 = src[lane + 192];

    float m = fmaxf(fmaxf(f4max(x0), f4max(x1)), fmaxf(f4max(x2), f4max(x3)));
    #pragma unroll
    for (int off = 32; off; off >>= 1) m = fmaxf(m, __shfl_xor(m, off));

    float s = 0.f;
    s += __expf(x0.x - m) + __expf(x0.y - m) + __expf(x0.z - m) + __expf(x0.w - m);
    s += __expf(x1.x - m) + __expf(x1.y - m) + __expf(x1.z - m) + __expf(x1.w - m);
    s += __expf(x2.x - m) + __expf(x2.y - m) + __expf(x2.z - m) + __expf(x2.w - m);
    s += __expf(x3.x - m) + __expf(x3.y - m) + __expf(x3.z - m) + __expf(x3.w - m);
    #pragma unroll
    for (int off = 32; off; off >>= 1) s += __shfl_xor(s, off);

    const float lse = m + __logf(s);

    if (lane == 0) blank_lp[cell] = x0.x - lse;   // vocab 0 lives in lane 0, x0.x

    if (u < lab) {
        int l = labels[b * (UU - 1) + u];
        l = min(max(l, 0), VV - 1);
        const int lane_l = (l >> 2) & 63;
        if (lane == lane_l) {
            const int j = l >> 8;
            const int c = l & 3;
            float val = (j == 0) ? f4comp(x0, c) : (j == 1) ? f4comp(x1, c)
                      : (j == 2) ? f4comp(x2, c) : f4comp(x3, c);
            label_lp[(b * TT + t) * (UU - 1) + u] = val - lse;
        }
    }
}

// Kernel 2: one block per batch. Stage blank+label into 160KB LDS (pitch 102),
// then wave 0 runs the anti-diagonal recursion entirely out of LDS + registers.
// Column mapping: lane owns u=lane (slot A) and u=lane+64 (slot B) -> LDS lane
// stride on a diagonal is 101 (odd) -> conflict-free ds_read; cross-column dep
// is shfl_up per slot (+ lane-0 wraparound from slot A of lane 63).
__global__ __launch_bounds__(256) void alpha_kernel(
        const float* __restrict__ blank_lp,
        const float* __restrict__ label_lp,
        const int*   __restrict__ lab_lens,   // [B]
        const int*   __restrict__ attn,       // [B, T]
        float* __restrict__ loss_b,           // [B]
        int*   __restrict__ valid_b) {        // [B]
    const int b    = blockIdx.x;
    const int tid  = threadIdx.x;
    const int lane = tid & 63;

    extern __shared__ float smem[];
    float* bs = smem;              // [TT][PAD] blank
    float* ls = smem + TT * PAD;   // [TT][PAD] label

    const float* bl = blank_lp + b * TT * UU;
    const float* lb = label_lp + b * TT * (UU - 1);

    // ---- stage blank/label into LDS (coalesced global reads) ----
    for (int i = tid; i < TT * UU; i += 256) {
        int t = i / UU, u = i - t * UU;
        bs[t * PAD + u] = bl[i];
    }
    for (int i = tid; i < TT * (UU - 1); i += 256) {
        int t = i / (UU - 1), u = i - t * (UU - 1);
        ls[t * PAD + u] = lb[i];
    }

    // ---- lengths (wave-redundant reduce, no LDS needed) ----
    int acc = 0;
    for (int i = lane; i < TT; i += 64) acc += attn[b * TT + i];
    #pragma unroll
    for (int off = 32; off; off >>= 1) acc += __shfl_xor(acc, off);
    const int tmax = min(max(acc, 1), TT) - 1;
    int lab = lab_lens[b];
    lab = min(max(lab, 0), UU - 1);
    const int ndiag = tmax + lab + 1;

    __syncthreads();
    if (tid >= 64) return;          // recursion is wave 0 only; no barriers after

    const int uA  = lane;                    // slot A column
    const int uB  = lane + 64;               // slot B column (logical)
    const int uBc = min(uB, UU - 1);         // clamped for LDS addressing
    const int eA  = max(uA - 1, 0);          // label col for A (lane0 value unused)
    const int eB  = uBc - 1;                 // = min(lane+63, 99)

    auto fetch = [&](int d, float& fbA, float& flA, float& fbB, float& flB) {
        int tA = min(max(d - uA, 0), TT - 1);
        int tB = min(max(d - uB, 0), TT - 1);
        fbA = bs[tA * PAD + uA];
        flA = ls[tA * PAD + eA];
        fbB = bs[tB * PAD + uBc];
        flB = ls[tB * PAD + eB];
    };

    float aA = -INFINITY, aB = -INFINITY;

    float cbA[4], clA[4], cbB[4], clB[4];
    float nbA[4], nlA[4], nbB[4], nlB[4];
    #pragma unroll
    for (int k = 0; k < 4; ++k) fetch(k, cbA[k], clA[k], cbB[k], clB[k]);

    const int ng = (ndiag + 3) >> 2;
    for (int g = 0; g < ng; ++g) {
        const int dbase = g * 4;
        #pragma unroll
        for (int k = 0; k < 4; ++k) fetch(dbase + 4 + k, nbA[k], nlA[k], nbB[k], nlB[k]);
        #pragma unroll
        for (int k = 0; k < 4; ++k) {
            const int d = dbase + k;
            if (d < ndiag) {                       // wave-uniform
                const float leftA = __shfl_up(aA, 1);
                const float upB   = __shfl_up(aB, 1);
                const float wrapB = __shfl(aA, 63);       // col 63 -> col 64 handoff
                const float leftB = (lane == 0) ? wrapB : upB;
                const int tA = d - uA;
                const int tB = d - uB;
                // slot A (branchless: compute full path, select boundaries)
                {
                    const float x  = aA + cbA[k];
                    const float y  = leftA + clA[k];
                    const float mx = fmaxf(x, y), mn = fminf(x, y);
                    const float full = mx + __logf(1.f + __expf(mn - mx));
                    const float v = (d == 0) ? cbA[k]
                                  : (uA == 0) ? x
                                  : (tA == 0) ? y
                                  : full;
                    const bool act = (uA <= lab) && (tA >= 0) && (tA <= tmax);
                    aA = act ? v : aA;
                }
                // slot B (uB >= 64 > 0 always; d==0 never active)
                {
                    const float x  = aB + cbB[k];
                    const float y  = leftB + clB[k];
                    const float mx = fmaxf(x, y), mn = fminf(x, y);
                    const float full = mx + __logf(1.f + __expf(mn - mx));
                    const float v = (tB == 0) ? y : full;
                    const bool act = (uB <= lab) && (tB >= 0) && (tB <= tmax);
                    aB = act ? v : aB;
                }
            }
        }
        #pragma unroll
        for (int k = 0; k < 4; ++k) { cbA[k] = nbA[k]; clA[k] = nlA[k];
                                      cbB[k] = nbB[k]; clB[k] = nlB[k]; }
    }

    // loss = -alpha[tmax, lab]; col lab lives on lane (lab & 63), slot (lab>=64)
    const float cand = (lab >= 64) ? aB : aA;
    const float v = __shfl(cand, lab & 63);
    if (lane == 0) {
        loss_b[b]  = -v;
        valid_b[b] = (lab > 0) ? 1 : 0;
    }
}

// Kernel 3: mean over valid batch elements.
__global__ void finalize_kernel(const float* __restrict__ loss_b,
                                const int* __restrict__ valid_b,
                                float* __restrict__ out) {
    if (threadIdx.x == 0 && blockIdx.x == 0) {
        float s = 0.f;
        int nv = 0;
        for (int b = 0; b < BB; ++b) {
            if (valid_b[b]) { s += loss_b[b]; ++nv; }
        }
        out[0] = s / (float)max(nv, 1);
    }
}

extern "C" void kernel_launch(void* const* d_in, const int* in_sizes, int n_in,
                              void* d_out, int out_size, void* d_ws, size_t ws_size,
                              hipStream_t stream) {
    const float* logits   = (const float*)d_in[0];
    const int*   labels   = (const int*)d_in[1];
    const int*   lab_lens = (const int*)d_in[2];
    const int*   attn     = (const int*)d_in[3];

    float* ws      = (float*)d_ws;
    float* blank   = ws;                           // B*T*U
    float* label   = blank + BB * TT * UU;         // B*T*(U-1)
    float* loss_b  = label + BB * TT * (UU - 1);   // B
    int*   valid_b = (int*)(loss_b + BB);          // B

    static bool attr_set = false;
    if (!attr_set) {
        hipFuncSetAttribute((const void*)alpha_kernel,
                            hipFuncAttributeMaxDynamicSharedMemorySize,
                            2 * TT * PAD * (int)sizeof(float));   // 163,200 B <= 160 KiB
        attr_set = true;
    }

    lse_kernel<<<(NCELL + 3) / 4, 256, 0, stream>>>(logits, labels, lab_lens, blank, label);
    alpha_kernel<<<BB, 256, 2 * TT * PAD * sizeof(float), stream>>>(
        blank, label, lab_lens, attn, loss_b, valid_b);
    finalize_kernel<<<1, 64, 0, stream>>>(loss_b, valid_b, (float*)d_out);
}